// Round 1
// baseline (2386.408 us; speedup 1.0000x reference)
//
#include <hip/hip_runtime.h>

// Problem constants
#define N_PIX 16384   // H*W = 128*128
#define CC    192
#define C3    576
#define BB    8
#define NHEADS 8
#define HD    24

// Workspace layout (floats):
//  Z0   @ 0          : 8*576*16384 = 75497472   (rgb post-dw qkv)
//  Z1   @ 75497472   : 75497472                 (ir  post-dw qkv)
//  Y    @ 150994944  : 576*16384 = 9437184      (per-batch qkv pre-dw tmp)
//  gpart@ 160432128  : 1024*624                 (partial gram + sumsq)
//  P    @ 161071104  : 128*576                  (softmaxed attn)
//  weff @ 161144832  : 16*192*192               (proj ∘ attn fused weights)
//  total = 161734656 floats = 646,938,624 bytes

// ---------------------------------------------------------------------------
// Generic fp32 tiled GEMM body: C[M,N_PIX] = A[M,K] @ B[K,N_PIX]
// 64(M) x 128(N) tile per block, 256 threads, 4x8 micro-tile per thread.
// ---------------------------------------------------------------------------
__device__ __forceinline__ void gemm_body(const float* __restrict__ A,
                                          const float* __restrict__ Bm,
                                          float* __restrict__ Cm,
                                          int K, long tileM, long tileN)
{
    __shared__ float As[16][68];    // [k][m], padded, 16B-aligned rows
    __shared__ float Bs[16][136];   // [k][n], padded, 16B-aligned rows

    const int tid = threadIdx.x;
    const int tx = tid & 15;        // 0..15 -> 8-wide col group
    const int ty = tid >> 4;        // 0..15 -> 4-wide row group

    float acc[4][8];
#pragma unroll
    for (int i = 0; i < 4; i++)
#pragma unroll
        for (int j = 0; j < 8; j++) acc[i][j] = 0.f;

    const int arow = tid >> 2;           // 0..63
    const int ak   = (tid & 3) << 2;     // 0,4,8,12
    const int brow = tid >> 4;           // 0..15
    const int bcol = (tid & 15) << 3;    // 0..120

    for (int k0 = 0; k0 < K; k0 += 16) {
        float4 av = *(const float4*)(A + (tileM + arow) * K + k0 + ak);
        As[ak + 0][arow] = av.x;
        As[ak + 1][arow] = av.y;
        As[ak + 2][arow] = av.z;
        As[ak + 3][arow] = av.w;
        const float* bsrc = Bm + (long)(k0 + brow) * N_PIX + tileN + bcol;
        *(float4*)&Bs[brow][bcol]     = *(const float4*)(bsrc);
        *(float4*)&Bs[brow][bcol + 4] = *(const float4*)(bsrc + 4);
        __syncthreads();
#pragma unroll
        for (int kk = 0; kk < 16; kk++) {
            float4 a4  = *(const float4*)&As[kk][ty << 2];
            float4 b4a = *(const float4*)&Bs[kk][tx << 3];
            float4 b4b = *(const float4*)&Bs[kk][(tx << 3) + 4];
            float am[4] = {a4.x, a4.y, a4.z, a4.w};
            float bm[8] = {b4a.x, b4a.y, b4a.z, b4a.w, b4b.x, b4b.y, b4b.z, b4b.w};
#pragma unroll
            for (int i = 0; i < 4; i++)
#pragma unroll
                for (int j = 0; j < 8; j++)
                    acc[i][j] = fmaf(am[i], bm[j], acc[i][j]);
        }
        __syncthreads();
    }
#pragma unroll
    for (int i = 0; i < 4; i++) {
        float4 o0 = make_float4(acc[i][0], acc[i][1], acc[i][2], acc[i][3]);
        float4 o1 = make_float4(acc[i][4], acc[i][5], acc[i][6], acc[i][7]);
        float* cp = Cm + (tileM + (ty << 2) + i) * (long)N_PIX + tileN + (tx << 3);
        *(float4*)cp       = o0;
        *(float4*)(cp + 4) = o1;
    }
}

// K1: y[576, N] = w_qkv[576,192] @ x[192, N]   (one batch)
__global__ __launch_bounds__(256) void gemm_qkv(const float* __restrict__ w,
                                                const float* __restrict__ x,
                                                float* __restrict__ y)
{
    gemm_body(w, x, y, CC, (long)blockIdx.y * 64, (long)blockIdx.x * 128);
}

// K6: out[o][b] = weff[o][b][192,192] @ V[o][b][192, N], all (o,b) in grid.z
__global__ __launch_bounds__(256) void gemm_out(const float* __restrict__ weff,
                                                const float* __restrict__ z0,
                                                const float* __restrict__ z1,
                                                float* __restrict__ out)
{
    const int z = blockIdx.z;         // o*8 + b
    const int o = z >> 3, b = z & 7;
    const float* A = weff + (long)z * (192 * 192);
    const float* V = (o == 0 ? z0 : z1) + (long)b * (C3 * N_PIX) + (long)(2 * CC) * N_PIX;
    float* C = out + (long)o * (BB * CC * N_PIX) + (long)b * (CC * N_PIX);
    gemm_body(A, V, C, CC, (long)blockIdx.y * 64, (long)blockIdx.x * 128);
}

// K2: depthwise 3x3 "SAME" conv, one batch. Y[576,128,128] -> Z[576,128,128]
__global__ __launch_bounds__(256) void dwconv3x3(const float* __restrict__ Y,
                                                 const float* __restrict__ wdw,
                                                 float* __restrict__ Z)
{
    const int p  = blockIdx.x * 256 + threadIdx.x;  // pixel 0..16383
    const int oc = blockIdx.y;                      // 0..575
    const int h = p >> 7, w = p & 127;
    const float* Yc = Y + (long)oc * N_PIX;
    const float* wk = wdw + oc * 9;
    float acc = 0.f;
#pragma unroll
    for (int ky = 0; ky < 3; ky++) {
        const int hy = h + ky - 1;
        if (hy < 0 || hy > 127) continue;
#pragma unroll
        for (int kx = 0; kx < 3; kx++) {
            const int wx = w + kx - 1;
            if (wx < 0 || wx > 127) continue;
            acc = fmaf(wk[ky * 3 + kx], Yc[hy * 128 + wx], acc);
        }
    }
    Z[(long)oc * N_PIX + p] = acc;
}

// K4a: partial Gram G[24,24] = Q[24,n] K[24,n]^T over an n-split, plus per-row
// sum-of-squares for Q and K. One wave per block; 3x3 micro-tile per thread.
// grid: (split=8, b*8+head=64, which=2). which0: rq·ik (attn_ir), which1: iq·rk.
__global__ __launch_bounds__(64) void gram_partial(const float* __restrict__ zrgb,
                                                   const float* __restrict__ zir,
                                                   float* __restrict__ gpart)
{
    const int split = blockIdx.x;
    const int bh    = blockIdx.y;
    const int which = blockIdx.z;
    const int b = bh >> 3, head = bh & 7;
    const long bofs = (long)b * C3 * N_PIX;
    const float* Q  = (which == 0 ? zrgb : zir) + bofs + (long)(head * HD) * N_PIX;
    const float* Kr = (which == 0 ? zir : zrgb) + bofs + (long)(CC + head * HD) * N_PIX;

    __shared__ float Qc[24][132];
    __shared__ float Kc[24][132];

    const int t = threadIdx.x;
    const int ci = t >> 3, di = t & 7;     // 8x8 thread grid over 3x3 tiles
    const int c0 = ci * 3, d0 = di * 3;

    float acc[3][3];
#pragma unroll
    for (int i = 0; i < 3; i++)
#pragma unroll
        for (int j = 0; j < 3; j++) acc[i][j] = 0.f;
    float ss = 0.f;

    const int n0base = split * 2048;
    for (int nc = 0; nc < 2048; nc += 128) {
        const long n0 = n0base + nc;
        if (t < 24) {
#pragma unroll 4
            for (int i = 0; i < 32; i++) {
                float4 v = *(const float4*)(Q + (long)t * N_PIX + n0 + i * 4);
                *(float4*)&Qc[t][i * 4] = v;
                ss += v.x * v.x + v.y * v.y + v.z * v.z + v.w * v.w;
            }
        } else if (t >= 32 && t < 56) {
            const int r = t - 32;
#pragma unroll 4
            for (int i = 0; i < 32; i++) {
                float4 v = *(const float4*)(Kr + (long)r * N_PIX + n0 + i * 4);
                *(float4*)&Kc[r][i * 4] = v;
                ss += v.x * v.x + v.y * v.y + v.z * v.z + v.w * v.w;
            }
        }
        __syncthreads();
#pragma unroll 4
        for (int kk = 0; kk < 128; kk += 4) {
            float4 qv[3], kv[3];
#pragma unroll
            for (int i = 0; i < 3; i++) qv[i] = *(const float4*)&Qc[c0 + i][kk];
#pragma unroll
            for (int j = 0; j < 3; j++) kv[j] = *(const float4*)&Kc[d0 + j][kk];
#pragma unroll
            for (int i = 0; i < 3; i++)
#pragma unroll
                for (int j = 0; j < 3; j++)
                    acc[i][j] += qv[i].x * kv[j].x + qv[i].y * kv[j].y +
                                 qv[i].z * kv[j].z + qv[i].w * kv[j].w;
        }
        __syncthreads();
    }

    const int g = (which * 64 + bh) * 8 + split;
    float* gp = gpart + (long)g * 624;
#pragma unroll
    for (int i = 0; i < 3; i++)
#pragma unroll
        for (int j = 0; j < 3; j++)
            gp[(c0 + i) * 24 + (d0 + j)] = acc[i][j];
    if (t < 24) gp[576 + t] = ss;
    else if (t >= 32 && t < 56) gp[600 + (t - 32)] = ss;
}

// K4b: reduce 8 split-partials, apply 1/max(norm,1e-12) scaling + temperature,
// row softmax over d. One block per (which,b,head).
__global__ __launch_bounds__(256) void gram_reduce_softmax(const float* __restrict__ gpart,
                                                           const float* __restrict__ temperature,
                                                           float* __restrict__ P)
{
    const int g = blockIdx.x;           // which*64 + b*8 + head
    const int head = g & 7;
    __shared__ float Gs[576];
    __shared__ float qs[24], ks[24], invq[24], invk[24];

    const int t = threadIdx.x;
    for (int e = t; e < 624; e += 256) {
        float s = 0.f;
        for (int sp = 0; sp < 8; sp++) s += gpart[(long)(g * 8 + sp) * 624 + e];
        if (e < 576) Gs[e] = s;
        else if (e < 600) qs[e - 576] = s;
        else ks[e - 600] = s;
    }
    __syncthreads();
    if (t < 24) {
        invq[t] = 1.f / fmaxf(sqrtf(qs[t]), 1e-12f);
        invk[t] = 1.f / fmaxf(sqrtf(ks[t]), 1e-12f);
    }
    __syncthreads();
    if (t < 24) {
        const float temp = temperature[head];
        float row[24];
        float m = -1e30f;
#pragma unroll
        for (int d = 0; d < 24; d++) {
            row[d] = Gs[t * 24 + d] * invq[t] * invk[d] * temp;
            m = fmaxf(m, row[d]);
        }
        float ssum = 0.f;
#pragma unroll
        for (int d = 0; d < 24; d++) {
            row[d] = expf(row[d] - m);
            ssum += row[d];
        }
        const float inv = 1.f / ssum;
#pragma unroll
        for (int d = 0; d < 24; d++)
            P[(long)g * 576 + t * 24 + d] = row[d] * inv;
    }
}

// K5: weff[o][b][co][head*24+d] = sum_hc wproj[co, head*24+hc] * P[1-o][b][head][hc][d]
__global__ __launch_bounds__(256) void build_weff(const float* __restrict__ wproj,
                                                  const float* __restrict__ P,
                                                  float* __restrict__ weff)
{
    const int o = blockIdx.z, b = blockIdx.y;
    const int e = blockIdx.x * 256 + threadIdx.x;   // 0..36863
    const int co = e / 192, col = e % 192;
    const int head = col / 24, d = col % 24;
    const int which = 1 - o;
    const float* Pp = P + (long)(which * 64 + b * 8 + head) * 576;
    const float* wp = wproj + co * 192 + head * 24;
    float acc = 0.f;
#pragma unroll
    for (int hc = 0; hc < 24; hc++)
        acc = fmaf(wp[hc], Pp[hc * 24 + d], acc);
    weff[((long)(o * 8 + b) * 192 + co) * 192 + col] = acc;
}

extern "C" void kernel_launch(void* const* d_in, const int* in_sizes, int n_in,
                              void* d_out, int out_size, void* d_ws, size_t ws_size,
                              hipStream_t stream) {
    (void)in_sizes; (void)n_in; (void)out_size; (void)ws_size;
    const float* rgb    = (const float*)d_in[0];
    const float* ir     = (const float*)d_in[1];
    const float* w_qkv  = (const float*)d_in[2];
    const float* w_dw   = (const float*)d_in[3];
    const float* w_proj = (const float*)d_in[4];
    const float* temp   = (const float*)d_in[5];
    float* out = (float*)d_out;
    float* ws  = (float*)d_ws;

    float* Z0    = ws;
    float* Z1    = ws + 75497472L;
    float* Y     = ws + 150994944L;
    float* gpart = ws + 160432128L;
    float* P     = ws + 161071104L;
    float* weff  = ws + 161144832L;

    // qkv 1x1 GEMM + depthwise 3x3, per (modality, batch) to bound Y tmp size
    for (int mod = 0; mod < 2; mod++) {
        const float* x = mod ? ir : rgb;
        float* Z = mod ? Z1 : Z0;
        for (int b = 0; b < 8; b++) {
            gemm_qkv<<<dim3(128, 9), 256, 0, stream>>>(w_qkv, x + (long)b * (CC * N_PIX), Y);
            dwconv3x3<<<dim3(64, C3), 256, 0, stream>>>(Y, w_dw, Z + (long)b * (C3 * N_PIX));
        }
    }
    // Gram + norms (fused), softmax, proj∘attn compose, final GEMM
    gram_partial<<<dim3(8, 64, 2), 64, 0, stream>>>(Z0, Z1, gpart);
    gram_reduce_softmax<<<128, 256, 0, stream>>>(gpart, temp, P);
    build_weff<<<dim3(144, 8, 2), 256, 0, stream>>>(w_proj, P, weff);
    gemm_out<<<dim3(128, 3, 16), 256, 0, stream>>>(weff, Z0, Z1, out);
}

// Round 2
// 1197.362 us; speedup vs baseline: 1.9931x; 1.9931x over previous
//
#include <hip/hip_runtime.h>

#define N_PIX 16384   // 128*128
#define CC    192
#define C3    576
#define KK    192     // GEMM K (=CC)
#define HD    24

typedef __attribute__((ext_vector_type(8))) short short8;   // 8 bf16 = 4 VGPR
typedef __attribute__((ext_vector_type(4))) float f32x4;    // MFMA acc

__device__ __forceinline__ unsigned short f2bf(float x) {
    unsigned u = __float_as_uint(x);
    u += 0x7fff + ((u >> 16) & 1);          // round-to-nearest-even
    return (unsigned short)(u >> 16);
}
__device__ __forceinline__ float bf2f(unsigned short s) {
    return __uint_as_float(((unsigned)s) << 16);
}
__device__ __forceinline__ int pack2(unsigned short lo, unsigned short hi) {
    return (int)(((unsigned)hi << 16) | (unsigned)lo);
}

// K0: fp32 -> bf16 bulk convert (vector of 4)
__global__ __launch_bounds__(256) void cvt_f32_bf16(const float* __restrict__ src,
                                                    unsigned short* __restrict__ dst, int n4) {
    int i = blockIdx.x * 256 + threadIdx.x;
    if (i < n4) {
        float4 v = ((const float4*)src)[i];
        ushort4 o;
        o.x = f2bf(v.x); o.y = f2bf(v.y); o.z = f2bf(v.z); o.w = f2bf(v.w);
        ((ushort4*)dst)[i] = o;
    }
}

// ---------------------------------------------------------------------------
// bf16 MFMA GEMM body: C[m0+192, n0+128] = A[*,192] @ B[192, N_PIX]
// 256 threads = 4 waves (2x2), wave tile 96x64, 16x16x32 bf16 MFMA.
// A: bf16 row-major [M][192]. B: fp32 or bf16 [192][N_PIX]. C: bf16 or fp32.
// ---------------------------------------------------------------------------
template<bool B_F32, bool C_BF16>
__device__ __forceinline__ void mfma_gemm(const unsigned short* __restrict__ Abf,
                                          const void* __restrict__ Bsrc,
                                          void* __restrict__ Cdst,
                                          int m0, int n0) {
    __shared__ unsigned short As[192][40];   // [m][k], +8 pad (80B stride, 2-way = free)
    __shared__ unsigned short Bs[128][40];   // [n][k]

    const int tid  = threadIdx.x;
    const int wave = tid >> 6, lane = tid & 63;
    const int quad = lane >> 4, l15 = lane & 15;
    const int wr = wave >> 1, wc = wave & 1;

    f32x4 acc[6][4];
#pragma unroll
    for (int i = 0; i < 6; i++)
#pragma unroll
        for (int j = 0; j < 4; j++) acc[i][j] = (f32x4)0.f;

    const int kq = tid & 3;        // B staging: k-chunk (kq*8)
    const int nq = tid >> 2;       // B staging: n-pair (nq*2)

    for (int k0 = 0; k0 < KK; k0 += 32) {
        // ---- stage A: 192x32 bf16, 3 x 16B per thread ----
#pragma unroll
        for (int c = 0; c < 3; c++) {
            int ch  = tid + c * 256;
            int row = ch >> 2, kc = (ch & 3) * 8;
            *(int4*)&As[row][kc] = *(const int4*)(Abf + (long)(m0 + row) * KK + k0 + kc);
        }
        // ---- stage B: 32x128, transpose to [n][k], cvt if fp32 ----
        if (B_F32) {
            const float* Bp = (const float*)Bsrc;
            float2 v[8];
#pragma unroll
            for (int j = 0; j < 8; j++)
                v[j] = *(const float2*)(Bp + (long)(k0 + kq * 8 + j) * N_PIX + n0 + nq * 2);
#pragma unroll
            for (int i = 0; i < 2; i++) {
                unsigned short us[8];
#pragma unroll
                for (int j = 0; j < 8; j++) us[j] = f2bf(i ? v[j].y : v[j].x);
                int4 pk = make_int4(pack2(us[0], us[1]), pack2(us[2], us[3]),
                                    pack2(us[4], us[5]), pack2(us[6], us[7]));
                *(int4*)&Bs[nq * 2 + i][kq * 8] = pk;
            }
        } else {
            const unsigned short* Bp = (const unsigned short*)Bsrc;
            ushort2 v[8];
#pragma unroll
            for (int j = 0; j < 8; j++)
                v[j] = *(const ushort2*)(Bp + (long)(k0 + kq * 8 + j) * N_PIX + n0 + nq * 2);
#pragma unroll
            for (int i = 0; i < 2; i++) {
                unsigned short us[8];
#pragma unroll
                for (int j = 0; j < 8; j++) us[j] = i ? v[j].y : v[j].x;
                int4 pk = make_int4(pack2(us[0], us[1]), pack2(us[2], us[3]),
                                    pack2(us[4], us[5]), pack2(us[6], us[7]));
                *(int4*)&Bs[nq * 2 + i][kq * 8] = pk;
            }
        }
        __syncthreads();

        short8 a[6], b[4];
#pragma unroll
        for (int mi = 0; mi < 6; mi++)
            a[mi] = *(const short8*)&As[wr * 96 + mi * 16 + l15][quad * 8];
#pragma unroll
        for (int ni = 0; ni < 4; ni++)
            b[ni] = *(const short8*)&Bs[wc * 64 + ni * 16 + l15][quad * 8];
#pragma unroll
        for (int mi = 0; mi < 6; mi++)
#pragma unroll
            for (int ni = 0; ni < 4; ni++)
                acc[mi][ni] = __builtin_amdgcn_mfma_f32_16x16x32_bf16(a[mi], b[ni], acc[mi][ni], 0, 0, 0);
        __syncthreads();
    }

    // ---- epilogue: C/D layout col=lane&15, row=quad*4+reg ----
#pragma unroll
    for (int mi = 0; mi < 6; mi++)
#pragma unroll
        for (int ni = 0; ni < 4; ni++)
#pragma unroll
            for (int r = 0; r < 4; r++) {
                int row = m0 + wr * 96 + mi * 16 + quad * 4 + r;
                int col = n0 + wc * 64 + ni * 16 + l15;
                if (C_BF16)
                    ((unsigned short*)Cdst)[(long)row * N_PIX + col] = f2bf(acc[mi][ni][r]);
                else
                    ((float*)Cdst)[(long)row * N_PIX + col] = acc[mi][ni][r];
            }
}

// K1: Y[z][576,N] = w_bf[576,192] @ x[z][192,N]   (z = mod*8+b), bf16 out
__global__ __launch_bounds__(256, 2) void qkv_mfma(const unsigned short* __restrict__ wbf,
                                                   const float* __restrict__ rgb,
                                                   const float* __restrict__ ir,
                                                   unsigned short* __restrict__ Ybf) {
    const int z = blockIdx.z, mod = z >> 3, b = z & 7;
    const float* x = (mod ? ir : rgb) + (long)b * CC * N_PIX;
    unsigned short* y = Ybf + (long)z * C3 * N_PIX;
    mfma_gemm<true, true>(wbf, x, y, blockIdx.y * 192, blockIdx.x * 128);
}

// K5: out[z][192,N] = weff_bf[z][192,192] @ V[z][192,N], fp32 out
__global__ __launch_bounds__(256, 2) void out_mfma(const unsigned short* __restrict__ weff,
                                                   const unsigned short* __restrict__ Zbf,
                                                   float* __restrict__ out) {
    const int z = blockIdx.z;   // o*8+b; V modality == o
    const unsigned short* V = Zbf + ((long)z * C3 + 2 * CC) * N_PIX;
    float* C = out + (long)z * CC * N_PIX;
    mfma_gemm<false, false>(weff + (long)z * CC * CC, V, C, 0, blockIdx.x * 128);
}

// K2: depthwise 3x3 SAME, bf16 in/out, all (z, ch) in grid, 4 px/thread
__global__ __launch_bounds__(256) void dwconv3x3(const unsigned short* __restrict__ Ybf,
                                                 const float* __restrict__ wdw,
                                                 unsigned short* __restrict__ Zbf) {
    const int z  = blockIdx.z;
    const int oc = blockIdx.y;
    const int p0 = (blockIdx.x * 256 + threadIdx.x) * 4;
    const unsigned short* Yc = Ybf + ((long)z * C3 + oc) * N_PIX;
    float wk[9];
#pragma unroll
    for (int i = 0; i < 9; i++) wk[i] = wdw[oc * 9 + i];
    ushort4 ov;
    unsigned short* po = (unsigned short*)&ov;
#pragma unroll
    for (int pp = 0; pp < 4; pp++) {
        const int p = p0 + pp, h = p >> 7, w = p & 127;
        float acc = 0.f;
#pragma unroll
        for (int ky = 0; ky < 3; ky++) {
            const int hy = h + ky - 1;
            if (hy < 0 || hy > 127) continue;
#pragma unroll
            for (int kx = 0; kx < 3; kx++) {
                const int wx = w + kx - 1;
                if (wx < 0 || wx > 127) continue;
                acc = fmaf(wk[ky * 3 + kx], bf2f(Yc[hy * 128 + wx]), acc);
            }
        }
        po[pp] = f2bf(acc);
    }
    *(ushort4*)(Zbf + ((long)z * C3 + oc) * N_PIX + p0) = ov;
}

// K3a: partial Gram G[24,24] + row sum-of-squares, bf16 input, fp32 math
__global__ __launch_bounds__(64) void gram_partial(const unsigned short* __restrict__ Zbf,
                                                   float* __restrict__ gpart) {
    const int split = blockIdx.x;
    const int bh    = blockIdx.y;
    const int which = blockIdx.z;
    const int b = bh >> 3, head = bh & 7;
    const int zq = (which == 0) ? b : 8 + b;
    const int zk = (which == 0) ? 8 + b : b;
    const unsigned short* Q  = Zbf + ((long)zq * C3 + head * HD) * N_PIX;
    const unsigned short* Kr = Zbf + ((long)zk * C3 + CC + head * HD) * N_PIX;

    __shared__ float Qc[24][132];
    __shared__ float Kc[24][132];

    const int t = threadIdx.x;
    const int ci = t >> 3, di = t & 7;
    const int c0 = ci * 3, d0 = di * 3;

    float acc[3][3];
#pragma unroll
    for (int i = 0; i < 3; i++)
#pragma unroll
        for (int j = 0; j < 3; j++) acc[i][j] = 0.f;
    float ss = 0.f;

    const int n0base = split * 2048;
    for (int nc = 0; nc < 2048; nc += 128) {
        const long n0 = n0base + nc;
        const unsigned short* src = nullptr;
        float* dstrow = nullptr;
        if (t < 24)               { src = Q  + (long)t * N_PIX + n0;        dstrow = Qc[t]; }
        else if (t >= 32 && t < 56) { src = Kr + (long)(t - 32) * N_PIX + n0; dstrow = Kc[t - 32]; }
        if (src) {
#pragma unroll 4
            for (int i = 0; i < 16; i++) {
                int4 raw = *(const int4*)(src + i * 8);
                float f[8];
                f[0] = bf2f((unsigned short)(raw.x & 0xffff)); f[1] = bf2f((unsigned short)((unsigned)raw.x >> 16));
                f[2] = bf2f((unsigned short)(raw.y & 0xffff)); f[3] = bf2f((unsigned short)((unsigned)raw.y >> 16));
                f[4] = bf2f((unsigned short)(raw.z & 0xffff)); f[5] = bf2f((unsigned short)((unsigned)raw.z >> 16));
                f[6] = bf2f((unsigned short)(raw.w & 0xffff)); f[7] = bf2f((unsigned short)((unsigned)raw.w >> 16));
                *(float4*)&dstrow[i * 8]     = make_float4(f[0], f[1], f[2], f[3]);
                *(float4*)&dstrow[i * 8 + 4] = make_float4(f[4], f[5], f[6], f[7]);
#pragma unroll
                for (int q = 0; q < 8; q++) ss = fmaf(f[q], f[q], ss);
            }
        }
        __syncthreads();
#pragma unroll 4
        for (int kk = 0; kk < 128; kk += 4) {
            float4 qv[3], kv[3];
#pragma unroll
            for (int i = 0; i < 3; i++) qv[i] = *(const float4*)&Qc[c0 + i][kk];
#pragma unroll
            for (int j = 0; j < 3; j++) kv[j] = *(const float4*)&Kc[d0 + j][kk];
#pragma unroll
            for (int i = 0; i < 3; i++)
#pragma unroll
                for (int j = 0; j < 3; j++)
                    acc[i][j] += qv[i].x * kv[j].x + qv[i].y * kv[j].y +
                                 qv[i].z * kv[j].z + qv[i].w * kv[j].w;
        }
        __syncthreads();
    }

    const int g = (which * 64 + bh) * 8 + split;
    float* gp = gpart + (long)g * 624;
#pragma unroll
    for (int i = 0; i < 3; i++)
#pragma unroll
        for (int j = 0; j < 3; j++)
            gp[(c0 + i) * 24 + (d0 + j)] = acc[i][j];
    if (t < 24) gp[576 + t] = ss;
    else if (t >= 32 && t < 56) gp[600 + (t - 32)] = ss;
}

// K3b: reduce splits, normalize, temperature, softmax -> P fp32
__global__ __launch_bounds__(256) void gram_reduce_softmax(const float* __restrict__ gpart,
                                                           const float* __restrict__ temperature,
                                                           float* __restrict__ P) {
    const int g = blockIdx.x;           // which*64 + b*8 + head
    const int head = g & 7;
    __shared__ float Gs[576];
    __shared__ float qs[24], ks[24], invq[24], invk[24];

    const int t = threadIdx.x;
    for (int e = t; e < 624; e += 256) {
        float s = 0.f;
        for (int sp = 0; sp < 8; sp++) s += gpart[(long)(g * 8 + sp) * 624 + e];
        if (e < 576) Gs[e] = s;
        else if (e < 600) qs[e - 576] = s;
        else ks[e - 600] = s;
    }
    __syncthreads();
    if (t < 24) {
        invq[t] = 1.f / fmaxf(sqrtf(qs[t]), 1e-12f);
        invk[t] = 1.f / fmaxf(sqrtf(ks[t]), 1e-12f);
    }
    __syncthreads();
    if (t < 24) {
        const float temp = temperature[head];
        float row[24];
        float m = -1e30f;
#pragma unroll
        for (int d = 0; d < 24; d++) {
            row[d] = Gs[t * 24 + d] * invq[t] * invk[d] * temp;
            m = fmaxf(m, row[d]);
        }
        float ssum = 0.f;
#pragma unroll
        for (int d = 0; d < 24; d++) {
            row[d] = expf(row[d] - m);
            ssum += row[d];
        }
        const float inv = 1.f / ssum;
#pragma unroll
        for (int d = 0; d < 24; d++)
            P[(long)g * 576 + t * 24 + d] = row[d] * inv;
    }
}

// K4: weff_bf[o][b] = wproj @ blockdiag(P[1-o][b])  (bf16 out)
__global__ __launch_bounds__(256) void build_weff(const float* __restrict__ wproj,
                                                  const float* __restrict__ P,
                                                  unsigned short* __restrict__ weff) {
    const int o = blockIdx.z, b = blockIdx.y;
    const int e = blockIdx.x * 256 + threadIdx.x;   // 0..36863
    const int co = e / 192, col = e % 192;
    const int head = col / 24, d = col % 24;
    const int which = 1 - o;
    const float* Pp = P + (long)(which * 64 + b * 8 + head) * 576;
    const float* wp = wproj + co * 192 + head * 24;
    float acc = 0.f;
#pragma unroll
    for (int hc = 0; hc < 24; hc++)
        acc = fmaf(wp[hc], Pp[hc * 24 + d], acc);
    weff[((long)(o * 8 + b) * 192 + co) * 192 + col] = f2bf(acc);
}

extern "C" void kernel_launch(void* const* d_in, const int* in_sizes, int n_in,
                              void* d_out, int out_size, void* d_ws, size_t ws_size,
                              hipStream_t stream) {
    (void)in_sizes; (void)n_in; (void)out_size; (void)ws_size;
    const float* rgb    = (const float*)d_in[0];
    const float* ir     = (const float*)d_in[1];
    const float* w_qkv  = (const float*)d_in[2];
    const float* w_dw   = (const float*)d_in[3];
    const float* w_proj = (const float*)d_in[4];
    const float* temp   = (const float*)d_in[5];
    float* out = (float*)d_out;

    char* wsb = (char*)d_ws;
    unsigned short* Y_bf    = (unsigned short*)(wsb);                 // 301,989,888 B
    unsigned short* Z_bf    = (unsigned short*)(wsb + 301989888L);    // 301,989,888 B
    unsigned short* w_bf    = (unsigned short*)(wsb + 603979776L);    //     221,184 B
    unsigned short* weff_bf = (unsigned short*)(wsb + 604200960L);    //   1,179,648 B
    float*          gpart   = (float*)(wsb + 605380608L);             //   2,555,904 B
    float*          P       = (float*)(wsb + 607936512L);             //     294,912 B

    cvt_f32_bf16<<<108, 256, 0, stream>>>(w_qkv, w_bf, 27648);
    qkv_mfma<<<dim3(128, 3, 16), 256, 0, stream>>>(w_bf, rgb, ir, Y_bf);
    dwconv3x3<<<dim3(16, 576, 16), 256, 0, stream>>>(Y_bf, w_dw, Z_bf);
    gram_partial<<<dim3(8, 64, 2), 64, 0, stream>>>(Z_bf, gpart);
    gram_reduce_softmax<<<128, 256, 0, stream>>>(gpart, temp, P);
    build_weff<<<dim3(144, 8, 2), 256, 0, stream>>>(w_proj, P, weff_bf);
    out_mfma<<<dim3(128, 1, 16), 256, 0, stream>>>(weff_bf, Z_bf, out);
}